// Round 3
// baseline (727.063 us; speedup 1.0000x reference)
//
#include <hip/hip_runtime.h>
#include <hip/hip_bf16.h>

#define Bb 8
#define Tt 48
#define HZ 24
#define Nn 1024
#define Hh 512
#define NHEAD 8

typedef short short8 __attribute__((ext_vector_type(8)));
typedef float f32x4 __attribute__((ext_vector_type(4)));

__device__ __forceinline__ ushort f2bf(float f) {
  uint u = __builtin_bit_cast(uint, f);
  u += 0x7FFFu + ((u >> 16) & 1u);
  return (ushort)(u >> 16);
}

// ---- prep: Wv^T in bf16 -> ws ----
__global__ void wvt_kernel(const float* __restrict__ Wv, ushort* __restrict__ Wvt) {
  int e = blockIdx.x * 256 + threadIdx.x;   // 512*512 = 262144
  int hd = e >> 9, c = e & 511;
  Wvt[e] = f2bf(Wv[c * 512 + hd]);          // Wvt[hd][c] = Wv[c][hd]
}

// ---- prep: attention weights (fp32 softmax) -> bf16 padded [B][8][32][64] ----
__global__ void attn_kernel(const float* __restrict__ xt, const float* __restrict__ tt,
                            const float* __restrict__ Wq, const float* __restrict__ bq,
                            const float* __restrict__ Wk, const float* __restrict__ bk,
                            ushort* __restrict__ attnp) {
  __shared__ float qs[24][65];
  __shared__ float ks_[48][65];
  __shared__ float sc[24][49];
  int bh = blockIdx.x;                       // 64 blocks
  int b = bh >> 3, h = bh & 7;
  int t = threadIdx.x;
  for (int e = t; e < 24 * 64; e += 256) {
    int i = e >> 6, dd = e & 63;
    float s = bq[h * 64 + dd];
    const float* r = tt + (b * 24 + i) * 64;
    #pragma unroll 8
    for (int c = 0; c < 64; ++c) s += r[c] * Wq[c * 512 + h * 64 + dd];
    qs[i][dd] = s;
  }
  for (int e = t; e < 48 * 64; e += 256) {
    int j = e >> 6, dd = e & 63;
    float s = bk[h * 64 + dd];
    const float* r = xt + (b * 48 + j) * 64;
    #pragma unroll 8
    for (int c = 0; c < 64; ++c) s += r[c] * Wk[c * 512 + h * 64 + dd];
    ks_[j][dd] = s;
  }
  __syncthreads();
  for (int e = t; e < 24 * 48; e += 256) {
    int i = e / 48, j = e - i * 48;
    float s = 0.f;
    #pragma unroll 8
    for (int dd = 0; dd < 64; ++dd) s += qs[i][dd] * ks_[j][dd];
    sc[i][j] = s * 0.125f;                   // / sqrt(64)
  }
  __syncthreads();
  if (t < 32) {
    int i = t;
    ushort* orow = attnp + ((size_t)bh * 32 + i) * 64;
    if (i < 24) {
      float mx = -1e30f;
      for (int j = 0; j < 48; ++j) mx = fmaxf(mx, sc[i][j]);
      float sum = 0.f;
      for (int j = 0; j < 48; ++j) { float e = expf(sc[i][j] - mx); sc[i][j] = e; sum += e; }
      float inv = 1.f / sum;
      for (int j = 0; j < 48; ++j) orow[j] = f2bf(sc[i][j] * inv);
      for (int j = 48; j < 64; ++j) orow[j] = 0;
    } else {
      for (int j = 0; j < 64; ++j) orow[j] = 0;
    }
  }
}

// ---- main fused kernel ----
// LDS: A[48][512] bf16 swizzled (48KB) + V^T [128][64] bf16 swizzled (16KB) = 64KB
// Wv^T fragments come straight from L2 into registers (no B staging, no barriers
// in the compute loop). V^T scratch is wave-private (rows w*32..w*32+31) ->
// exactly ONE __syncthreads() per block (after the A-stage).
#define A_BASE 0
#define V_BASE 49152

__global__ __launch_bounds__(256, 2) void main_kernel(
    const float* __restrict__ EH, const ushort* __restrict__ Wvt,
    const ushort* __restrict__ attnp, const float* __restrict__ bv,
    float* __restrict__ out) {
  __shared__ __align__(128) char smem[65536];
  int bid = blockIdx.x;
  int b = bid >> 10, n = bid & 1023;
  int t = threadIdx.x;
  int lane = t & 63, w = t >> 6;
  int rowl = lane & 15;
  int colb = (lane >> 4) << 3;               // fragment k-offset in elements

  // zero V^T pad cols 48..63 once (wave-private rows; stale LDS could be NaN)
  {
    int r = w * 32 + (lane >> 1);
    int off = (r << 7) + 96 + ((lane & 1) << 4);
    off ^= (r & 7) << 4;
    *(uint4*)(smem + V_BASE + off) = make_uint4(0, 0, 0, 0);
  }

  // stage A: EH[b][j][n][0..511] fp32 -> bf16 LDS (swizzle ^((j&7)<<4))
  {
    const float* ehb = EH + (((size_t)b * Tt) * Nn + n) * Hh;
    #pragma unroll 8
    for (int it = 0; it < 24; ++it) {
      int f = it * 256 + t;                  // 48 rows * 128 float4
      int j = f >> 7, c4 = f & 127;
      float4 v = *(const float4*)(ehb + (size_t)j * (Nn * Hh) + c4 * 4);
      uint2 p;
      p.x = (uint)f2bf(v.x) | ((uint)f2bf(v.y) << 16);
      p.y = (uint)f2bf(v.z) | ((uint)f2bf(v.w) << 16);
      int off = (j << 10) + (c4 << 3);
      off ^= (j & 7) << 4;
      *(uint2*)(smem + A_BASE + off) = p;
    }
  }
  __syncthreads();   // the ONLY barrier: A visible to all waves

  for (int ch = 0; ch < 4; ++ch) {
    // B-fragment base pointers: row = ch*128 + w*32 + nn*16 + rowl, col = colb
    const ushort* bp0 = Wvt + ((size_t)(ch * 128 + w * 32 + rowl)) * 512 + colb;
    const ushort* bp1 = bp0 + 16 * 512;

    f32x4 acc[3][2] = {};
    short8 bc[2][2];                         // [ki][nn], current kb
    bc[0][0] = *(const short8*)(bp0);
    bc[0][1] = *(const short8*)(bp1);
    bc[1][0] = *(const short8*)(bp0 + 32);
    bc[1][1] = *(const short8*)(bp1 + 32);

    #pragma unroll
    for (int kb = 0; kb < 8; ++kb) {
      short8 bn[2][2];
      if (kb < 7) {                          // register-prefetch next K-slice (L2)
        int o = (kb + 1) * 64;
        bn[0][0] = *(const short8*)(bp0 + o);
        bn[0][1] = *(const short8*)(bp1 + o);
        bn[1][0] = *(const short8*)(bp0 + o + 32);
        bn[1][1] = *(const short8*)(bp1 + o + 32);
      }
      #pragma unroll
      for (int ki = 0; ki < 2; ++ki) {
        short8 af[3];
        int kc = kb * 64 + ki * 32 + colb;
        #pragma unroll
        for (int m = 0; m < 3; ++m) {
          int j = m * 16 + rowl;
          int off = (j << 10) + (kc << 1);
          off ^= (j & 7) << 4;
          af[m] = *(const short8*)(smem + A_BASE + off);
        }
        #pragma unroll
        for (int m = 0; m < 3; ++m) {
          acc[m][0] = __builtin_amdgcn_mfma_f32_16x16x32_bf16(af[m], bc[ki][0], acc[m][0], 0, 0, 0);
          acc[m][1] = __builtin_amdgcn_mfma_f32_16x16x32_bf16(af[m], bc[ki][1], acc[m][1], 0, 0, 0);
        }
      }
      if (kb < 7) {
        bc[0][0] = bn[0][0]; bc[0][1] = bn[0][1];
        bc[1][0] = bn[1][0]; bc[1][1] = bn[1][1];
      }
    }

    // hoist attn fragment loads (L2) so they're in flight during V^T writes
    int h = 2 * ch + (w >> 1);
    short8 pa[2][2];                         // [ks][itl]
    #pragma unroll
    for (int ks = 0; ks < 2; ++ks)
      #pragma unroll
      for (int itl = 0; itl < 2; ++itl) {
        int i = itl * 16 + rowl;
        pa[ks][itl] = *(const short8*)(attnp + (((size_t)(b * 8 + h) * 32 + i) * 64) + ks * 32 + colb);
      }

    // acc -> V^T bf16 in LDS (wave-private rows, swizzled)
    #pragma unroll
    for (int m = 0; m < 3; ++m) {
      #pragma unroll
      for (int nn = 0; nn < 2; ++nn) {
        int hd = w * 32 + nn * 16 + rowl;
        int j0 = m * 16 + ((lane >> 4) << 2);
        uint2 p;
        p.x = (uint)f2bf(acc[m][nn][0]) | ((uint)f2bf(acc[m][nn][1]) << 16);
        p.y = (uint)f2bf(acc[m][nn][2]) | ((uint)f2bf(acc[m][nn][3]) << 16);
        int off = (hd << 7) + (j0 << 1);
        off ^= (hd & 7) << 4;
        *(uint2*)(smem + V_BASE + off) = p;
      }
    }
    asm volatile("s_waitcnt lgkmcnt(0)" ::: "memory");  // V writes done (same wave reads next)

    // stage 2: X[i,hd] = sum_j attn[h,i,j] * V[j,hd]
    f32x4 x[2][2] = {};
    #pragma unroll
    for (int ks = 0; ks < 2; ++ks) {
      short8 vb[2];
      #pragma unroll
      for (int nn = 0; nn < 2; ++nn) {
        int hd = w * 32 + nn * 16 + rowl;
        int off = (hd << 7) + ((ks * 32 + colb) << 1);
        off ^= (hd & 7) << 4;
        vb[nn] = *(const short8*)(smem + V_BASE + off);
      }
      #pragma unroll
      for (int itl = 0; itl < 2; ++itl)
        #pragma unroll
        for (int nn = 0; nn < 2; ++nn)
          x[itl][nn] = __builtin_amdgcn_mfma_f32_16x16x32_bf16(pa[ks][itl], vb[nn], x[itl][nn], 0, 0, 0);
    }

    // store X rows i<24 (+bv; softmax rows sum to 1 so bias passes through)
    #pragma unroll
    for (int itl = 0; itl < 2; ++itl) {
      int ib = itl * 16 + ((lane >> 4) << 2);
      #pragma unroll
      for (int nn = 0; nn < 2; ++nn) {
        int hd = ch * 128 + w * 32 + nn * 16 + rowl;
        float bvv = bv[hd];
        #pragma unroll
        for (int r = 0; r < 4; ++r) {
          int i = ib + r;
          if (i < 24)
            out[(((size_t)b * HZ + i) * Nn + n) * Hh + hd] = x[itl][nn][r] + bvv;
        }
      }
    }
  }
}

extern "C" void kernel_launch(void* const* d_in, const int* in_sizes, int n_in,
                              void* d_out, int out_size, void* d_ws, size_t ws_size,
                              hipStream_t stream) {
  (void)in_sizes; (void)n_in; (void)out_size; (void)ws_size;
  const float* EH = (const float*)d_in[0];
  const float* xt = (const float*)d_in[1];
  const float* tt = (const float*)d_in[2];
  const float* Wq = (const float*)d_in[3];
  const float* bq = (const float*)d_in[4];
  const float* Wk = (const float*)d_in[5];
  const float* bk = (const float*)d_in[6];
  const float* Wv = (const float*)d_in[7];
  const float* bv = (const float*)d_in[8];
  float* out = (float*)d_out;
  ushort* Wvt = (ushort*)d_ws;                                   // 512 KB
  ushort* attnp = (ushort*)((char*)d_ws + 512 * 1024);           // 256 KB

  wvt_kernel<<<1024, 256, 0, stream>>>(Wv, Wvt);
  attn_kernel<<<64, 256, 0, stream>>>(xt, tt, Wq, bq, Wk, bk, attnp);
  main_kernel<<<8192, 256, 0, stream>>>(EH, Wvt, attnp, bv, out);
}

// Round 6
// 468.916 us; speedup vs baseline: 1.5505x; 1.5505x over previous
//
#include <hip/hip_runtime.h>
#include <hip/hip_bf16.h>

#define Bb 8
#define Tt 48
#define HZ 24
#define Nn 1024
#define Hh 512
#define NHEAD 8

typedef short short8 __attribute__((ext_vector_type(8)));
typedef float f32x4 __attribute__((ext_vector_type(4)));

__device__ __forceinline__ ushort f2bf(float f) {
  uint u = __builtin_bit_cast(uint, f);
  u += 0x7FFFu + ((u >> 16) & 1u);
  return (ushort)(u >> 16);
}

// ---- prep: repack Wv into per-lane MFMA fragment order ----
// W2[ch][w][kb][f=ki*2+nn][lane][e]  (ushort), 512KB total.
// Fragment element = Wv^T[row][col] = Wv[col][row],
//   row = ch*128 + w*32 + nn*16 + (lane&15)
//   col = kb*64 + ki*32 + ((lane>>4)<<3) + e
__global__ void wvt2_kernel(const float* __restrict__ Wv, ushort* __restrict__ W2) {
  int t = blockIdx.x * 256 + threadIdx.x;    // [0, 262144)
  int e = t & 7;
  int lane = (t >> 3) & 63;
  int f = (t >> 9) & 3;
  int kb = (t >> 11) & 7;
  int w = (t >> 14) & 3;
  int ch = t >> 16;
  int ki = f >> 1, nn = f & 1;
  int row = ch * 128 + w * 32 + nn * 16 + (lane & 15);
  int col = kb * 64 + ki * 32 + ((lane >> 4) << 3) + e;
  W2[t] = f2bf(Wv[col * 512 + row]);
}

// ---- prep: attention weights (fp32 softmax) -> bf16 padded [B][8][32][64] ----
__global__ void attn_kernel(const float* __restrict__ xt, const float* __restrict__ tt,
                            const float* __restrict__ Wq, const float* __restrict__ bq,
                            const float* __restrict__ Wk, const float* __restrict__ bk,
                            ushort* __restrict__ attnp) {
  __shared__ float qs[24][65];
  __shared__ float ks_[48][65];
  __shared__ float sc[24][49];
  int bh = blockIdx.x;                       // 64 blocks
  int b = bh >> 3, h = bh & 7;
  int t = threadIdx.x;
  for (int e = t; e < 24 * 64; e += 256) {
    int i = e >> 6, dd = e & 63;
    float s = bq[h * 64 + dd];
    const float* r = tt + (b * 24 + i) * 64;
    #pragma unroll 8
    for (int c = 0; c < 64; ++c) s += r[c] * Wq[c * 512 + h * 64 + dd];
    qs[i][dd] = s;
  }
  for (int e = t; e < 48 * 64; e += 256) {
    int j = e >> 6, dd = e & 63;
    float s = bk[h * 64 + dd];
    const float* r = xt + (b * 48 + j) * 64;
    #pragma unroll 8
    for (int c = 0; c < 64; ++c) s += r[c] * Wk[c * 512 + h * 64 + dd];
    ks_[j][dd] = s;
  }
  __syncthreads();
  for (int e = t; e < 24 * 48; e += 256) {
    int i = e / 48, j = e - i * 48;
    float s = 0.f;
    #pragma unroll 8
    for (int dd = 0; dd < 64; ++dd) s += qs[i][dd] * ks_[j][dd];
    sc[i][j] = s * 0.125f;                   // / sqrt(64)
  }
  __syncthreads();
  if (t < 32) {
    int i = t;
    ushort* orow = attnp + ((size_t)bh * 32 + i) * 64;
    if (i < 24) {
      float mx = -1e30f;
      for (int j = 0; j < 48; ++j) mx = fmaxf(mx, sc[i][j]);
      float sum = 0.f;
      for (int j = 0; j < 48; ++j) { float e = expf(sc[i][j] - mx); sc[i][j] = e; sum += e; }
      float inv = 1.f / sum;
      for (int j = 0; j < 48; ++j) orow[j] = f2bf(sc[i][j] * inv);
      for (int j = 48; j < 64; ++j) orow[j] = 0;
    } else {
      for (int j = 0; j < 64; ++j) orow[j] = 0;
    }
  }
}

// ---- main fused kernel ----
// LDS: A[48][512] bf16 swizzled (48KB) + V^T per-wave [32][64] bf16 swizzled (16KB) = 64KB.
// B fragments live in REGISTERS, streamed coalesced from repacked W2 (L1/L2-resident),
// 1-deep prefetch incl. across ch. ONE __syncthreads per block; no LDS-DMA.
#define A_BASE 0
#define V_BASE 49152

__global__ __launch_bounds__(256, 2) void main_kernel(
    const float* __restrict__ EH, const ushort* __restrict__ W2,
    const ushort* __restrict__ attnp, const float* __restrict__ bv,
    float* __restrict__ out) {
  __shared__ __align__(128) char smem[65536];
  int bid = blockIdx.x;
  int b = bid >> 10, n = bid & 1023;
  int t = threadIdx.x;
  int lane = t & 63, w = t >> 6;
  int rowl = lane & 15;
  int colb = (lane >> 4) << 3;
  char* vbuf = smem + V_BASE + w * 4096;     // wave-private V^T scratch

  // hoist bv: bvr[ch][nn]
  float bvr[4][2];
  #pragma unroll
  for (int c = 0; c < 4; ++c)
    #pragma unroll
    for (int nn = 0; nn < 2; ++nn)
      bvr[c][nn] = bv[c * 128 + w * 32 + nn * 16 + rowl];

  // zero V^T pad cols 48..63 once (wave-private; V writes only touch cols 0..47)
  {
    int lr = lane >> 1;
    int off = (lr << 7) + ((96 + ((lane & 1) << 4)) ^ ((lr & 7) << 4));
    *(uint4*)(vbuf + off) = make_uint4(0, 0, 0, 0);
  }

  // B fragment stream base for this wave (per (ch,w): 16384 ushorts = 32KB;
  // per-ch stride = 4*16384 = 65536 ushorts)
  const ushort* wp0 = W2 + (size_t)w * 16384 + lane * 8;

  // prologue: prefetch (ch=0, kb=0) fragments
  short8 bc[4], bn[4];
  #pragma unroll
  for (int f = 0; f < 4; ++f) bc[f] = *(const short8*)(wp0 + f * 512);

  // stage A: EH[b][j][n][0..511] fp32 -> bf16 LDS (swizzle ^((j&7)<<4))
  {
    const float* ehb = EH + (((size_t)b * Tt) * Nn + n) * Hh;
    #pragma unroll 8
    for (int it = 0; it < 24; ++it) {
      int f = it * 256 + t;                  // 48 rows * 128 float4
      int j = f >> 7, c4 = f & 127;
      float4 v = *(const float4*)(ehb + (size_t)j * (Nn * Hh) + c4 * 4);
      uint2 p;
      p.x = (uint)f2bf(v.x) | ((uint)f2bf(v.y) << 16);
      p.y = (uint)f2bf(v.z) | ((uint)f2bf(v.w) << 16);
      int off = (j << 10) + (c4 << 3);
      off ^= (j & 7) << 4;
      *(uint2*)(smem + A_BASE + off) = p;
    }
  }
  __syncthreads();   // the ONLY barrier: A visible to all waves

  #pragma unroll
  for (int ch = 0; ch < 4; ++ch) {
    const ushort* wp = W2 + (size_t)(ch * 4 + w) * 16384 + lane * 8;
    f32x4 acc[3][2] = {};
    #pragma unroll
    for (int kb = 0; kb < 8; ++kb) {
      // 1-deep register prefetch (crosses the ch boundary; next ch = +65536 ushorts)
      if (kb < 7) {
        #pragma unroll
        for (int f = 0; f < 4; ++f)
          bn[f] = *(const short8*)(wp + (kb + 1) * 2048 + f * 512);
      } else if (ch < 3) {
        #pragma unroll
        for (int f = 0; f < 4; ++f)
          bn[f] = *(const short8*)(wp + 65536 + f * 512);
      }
      #pragma unroll
      for (int ki = 0; ki < 2; ++ki) {
        short8 af[3];
        int kc = kb * 64 + ki * 32 + colb;
        #pragma unroll
        for (int m = 0; m < 3; ++m) {
          int j = m * 16 + rowl;
          int off = (j << 10) + (kc << 1);
          off ^= (j & 7) << 4;
          af[m] = *(const short8*)(smem + A_BASE + off);
        }
        #pragma unroll
        for (int m = 0; m < 3; ++m) {
          acc[m][0] = __builtin_amdgcn_mfma_f32_16x16x32_bf16(af[m], bc[ki * 2 + 0], acc[m][0], 0, 0, 0);
          acc[m][1] = __builtin_amdgcn_mfma_f32_16x16x32_bf16(af[m], bc[ki * 2 + 1], acc[m][1], 0, 0, 0);
        }
      }
      #pragma unroll
      for (int f = 0; f < 4; ++f) bc[f] = bn[f];
    }

    // hoist attn fragment loads (L2) so they fly during V^T writes
    int h = 2 * ch + (w >> 1);
    short8 pa[2][2];                         // [ks][itl]
    #pragma unroll
    for (int ks = 0; ks < 2; ++ks)
      #pragma unroll
      for (int itl = 0; itl < 2; ++itl) {
        int i = itl * 16 + rowl;
        pa[ks][itl] = *(const short8*)(attnp + (((size_t)(b * 8 + h) * 32 + i) * 64) + ks * 32 + colb);
      }

    // acc -> V^T bf16 (wave-private, swizzled); rows lr = local hd in [0,32)
    #pragma unroll
    for (int m = 0; m < 3; ++m) {
      #pragma unroll
      for (int nn = 0; nn < 2; ++nn) {
        int lr = nn * 16 + rowl;
        int j0 = m * 16 + ((lane >> 4) << 2);
        uint2 p;
        p.x = (uint)f2bf(acc[m][nn][0]) | ((uint)f2bf(acc[m][nn][1]) << 16);
        p.y = (uint)f2bf(acc[m][nn][2]) | ((uint)f2bf(acc[m][nn][3]) << 16);
        int off = (lr << 7) + ((j0 << 1) ^ ((lr & 7) << 4));
        *(uint2*)(vbuf + off) = p;
      }
    }
    asm volatile("s_waitcnt lgkmcnt(0)" ::: "memory");  // V writes serviced (same-wave reads next)
    __builtin_amdgcn_sched_barrier(0);

    // stage 2: X[i,hd] = sum_j attn[h,i,j] * V[j,hd]
    f32x4 x[2][2] = {};
    #pragma unroll
    for (int ks = 0; ks < 2; ++ks) {
      short8 vb[2];
      #pragma unroll
      for (int nn = 0; nn < 2; ++nn) {
        int lr = nn * 16 + rowl;
        int off = (lr << 7) + (((ks * 32 + colb) << 1) ^ ((lr & 7) << 4));
        vb[nn] = *(const short8*)(vbuf + off);
      }
      #pragma unroll
      for (int itl = 0; itl < 2; ++itl)
        #pragma unroll
        for (int nn = 0; nn < 2; ++nn)
          x[itl][nn] = __builtin_amdgcn_mfma_f32_16x16x32_bf16(pa[ks][itl], vb[nn], x[itl][nn], 0, 0, 0);
    }

    // store X rows i<24 (+bv; softmax rows sum to 1 so bias passes through)
    #pragma unroll
    for (int itl = 0; itl < 2; ++itl) {
      int ib = itl * 16 + ((lane >> 4) << 2);
      #pragma unroll
      for (int nn = 0; nn < 2; ++nn) {
        int hd = ch * 128 + w * 32 + nn * 16 + rowl;
        float bvv = bvr[ch][nn];
        #pragma unroll
        for (int r = 0; r < 4; ++r) {
          int i = ib + r;
          if (i < 24)
            out[(((size_t)b * HZ + i) * Nn + n) * Hh + hd] = x[itl][nn][r] + bvv;
        }
      }
    }
  }
}

extern "C" void kernel_launch(void* const* d_in, const int* in_sizes, int n_in,
                              void* d_out, int out_size, void* d_ws, size_t ws_size,
                              hipStream_t stream) {
  (void)in_sizes; (void)n_in; (void)out_size; (void)ws_size;
  const float* EH = (const float*)d_in[0];
  const float* xt = (const float*)d_in[1];
  const float* tt = (const float*)d_in[2];
  const float* Wq = (const float*)d_in[3];
  const float* bq = (const float*)d_in[4];
  const float* Wk = (const float*)d_in[5];
  const float* bk = (const float*)d_in[6];
  const float* Wv = (const float*)d_in[7];
  const float* bv = (const float*)d_in[8];
  float* out = (float*)d_out;
  ushort* W2 = (ushort*)d_ws;                                    // 512 KB
  ushort* attnp = (ushort*)((char*)d_ws + 512 * 1024);           // 256 KB

  wvt2_kernel<<<1024, 256, 0, stream>>>(Wv, W2);
  attn_kernel<<<64, 256, 0, stream>>>(xt, tt, Wq, bq, Wk, bk, attnp);
  main_kernel<<<8192, 256, 0, stream>>>(EH, W2, attnp, bv, out);
}